// Round 7
// baseline (1140.735 us; speedup 1.0000x reference)
//
#include <hip/hip_runtime.h>

#define TOK   8192
#define DD    1024
#define FF    4096
#define EE    8
#define TWOF  8192
#define NSLOT 16384   // TOK * top_k(2)
#define PADT  18432   // NSLOT + 8*256 (per-expert 256-row padding bound)

typedef unsigned short u16;
typedef float  f32x16 __attribute__((ext_vector_type(16)));
typedef __bf16 bf16x8 __attribute__((ext_vector_type(8)));

__device__ __forceinline__ u16 f2b(float f) {
  unsigned u = __builtin_bit_cast(unsigned, f);
  u += 0x7fffu + ((u >> 16) & 1u);   // RNE; inputs finite
  return (u16)(u >> 16);
}

__device__ __forceinline__ void ldslds16(const void* g, void* l) {
  __builtin_amdgcn_global_load_lds((const __attribute__((address_space(1))) void*)g,
                                   (__attribute__((address_space(3))) void*)l, 16, 0, 0);
}

// ---------------- gate: logits, softmax, top-2, counts ----------------
__global__ void gate_kernel(const float* __restrict__ x, const float* __restrict__ gw,
                            const float* __restrict__ gb, int* __restrict__ counts,
                            int* __restrict__ eidx, int* __restrict__ epos,
                            float* __restrict__ ew) {
  const int wave = threadIdx.x >> 6, lane = threadIdx.x & 63;
  const int t = blockIdx.x * 4 + wave;
  float acc[EE] = {0,0,0,0,0,0,0,0};
  const float* xr = x + (size_t)t * DD;
  for (int d = lane; d < DD; d += 64) {
    float xv = xr[d];
    const float* g = gw + (size_t)d * EE;
#pragma unroll
    for (int e = 0; e < EE; ++e) acc[e] += xv * g[e];
  }
#pragma unroll
  for (int e = 0; e < EE; ++e)
#pragma unroll
    for (int off = 32; off > 0; off >>= 1) acc[e] += __shfl_down(acc[e], off);
  if (lane == 0) {
    float l[EE];
#pragma unroll
    for (int e = 0; e < EE; ++e) l[e] = acc[e] + gb[e];
    int i0 = 0;
    for (int e = 1; e < EE; ++e) if (l[e] > l[i0]) i0 = e;
    int i1 = (i0 == 0) ? 1 : 0;
    for (int e = 0; e < EE; ++e) { if (e == i0) continue; if (l[e] > l[i1]) i1 = e; }
    float m = l[0];
    for (int e = 1; e < EE; ++e) m = fmaxf(m, l[e]);
    float s = 0.f, p[EE];
    for (int e = 0; e < EE; ++e) { p[e] = __expf(l[e] - m); s += p[e]; }
    float w0 = p[i0] / s, w1 = p[i1] / s;
    int p0 = atomicAdd(&counts[i0], 1);
    int p1 = atomicAdd(&counts[i1], 1);
    eidx[2*t] = i0; eidx[2*t+1] = i1;
    epos[2*t] = p0; epos[2*t+1] = p1;
    ew[2*t] = w0;  ew[2*t+1] = w1;
  }
}

// setup: meta[0..7]=opad (256-aligned expert slot offsets), meta[8..16]=tm-block prefix
__global__ void setup_kernel(const int* __restrict__ counts, int* __restrict__ meta) {
  if (threadIdx.x == 0 && blockIdx.x == 0) {
    int s = 0, tm = 0;
    for (int e = 0; e < EE; ++e) {
      meta[e] = s;
      meta[8 + e] = tm;
      s  += (counts[e] + 255) & ~255;
      tm += (counts[e] + 255) >> 8;
    }
    meta[16] = tm;
  }
}

__global__ void slot_kernel(const int* __restrict__ eidx, const int* __restrict__ epos,
                            const float* __restrict__ ew, const int* __restrict__ meta,
                            int* __restrict__ s2t, float* __restrict__ swt,
                            int* __restrict__ t2s) {
  int i = blockIdx.x * 256 + threadIdx.x;           // 0..2T-1
  int e = eidx[i];
  int slot = meta[e] + epos[i];
  s2t[slot] = i >> 1;
  swt[slot] = ew[i];
  t2s[i] = slot;
}

// ---------------- conversions ----------------
__global__ void cvtx_kernel(const float* __restrict__ x, u16* __restrict__ xb) {
  int i = blockIdx.x * 256 + threadIdx.x;           // 4 elements each
  float4 v = ((const float4*)x)[i];
  unsigned lo = (unsigned)f2b(v.x) | ((unsigned)f2b(v.y) << 16);
  unsigned hi = (unsigned)f2b(v.z) | ((unsigned)f2b(v.w) << 16);
  ((uint2*)xb)[i] = make_uint2(lo, hi);
}

__global__ void gather_kernel(const u16* __restrict__ xb, const int* __restrict__ s2t,
                              u16* __restrict__ xg) {
  int i = blockIdx.x * 256 + threadIdx.x;           // 16B chunks, PADT rows
  int row = i >> 7, c = i & 127;
  int tok = s2t[row];                                // pad slots are 0 (memset)
  ((int4*)xg)[(size_t)row * 128 + c] = ((const int4*)xb)[(size_t)tok * 128 + c];
}

// transpose-convert weights: dst[seg][n][k] (bf16) = src[seg][k][oc(n)] (f32)
// permute (w1 only): interleave a/b halves in 32-col groups (SwiGLU pairing, 32x32 MFMA)
__global__ void wt_kernel(const float* __restrict__ srcS, const float* __restrict__ srcR,
                          u16* __restrict__ dst, int K, int N, int permute) {
  __shared__ float tile[32][33];
  const int seg = blockIdx.z;
  const float* src = (seg == 0) ? srcS : srcR + (size_t)(seg - 1) * K * N;
  const int pc0 = blockIdx.x * 32, k0 = blockIdx.y * 32;
  const int tid = threadIdx.x;
  {
    int kk = tid >> 3, j4 = (tid & 7) << 2;
    const float* srow = src + (size_t)(k0 + kk) * N;
#pragma unroll
    for (int q = 0; q < 4; ++q) {
      int n = pc0 + j4 + q;
      int oc = permute ? (((n >> 6) << 5) + (n & 31) + ((n & 32) ? FF : 0)) : n;
      tile[kk][j4 + q] = srow[oc];
    }
  }
  __syncthreads();
  {
    int pp = tid >> 3, kq = (tid & 7) << 2;
    u16* drow = dst + (size_t)seg * N * K + (size_t)(pc0 + pp) * K + k0 + kq;
#pragma unroll
    for (int q = 0; q < 4; ++q) drow[q] = f2b(tile[kq + q][pp]);
  }
}

// ================= 256x256x64 ring-pipelined GEMM core =================
// 8 waves (2M x 4N), per-wave 128x64 (4x2 frags of 32x32x16). 1 block/CU.
// LDS 160 KiB: A ring-3 @0 (3x32K), B ring-2 @98304 (2x32K).
// A staged t+2 ahead (~2 tiles latency budget); B staged t+1 ahead (L2-hot).
// Cross-phase register prefetch; one barrier + counted vmcnt(4) per tile.

#define STG_A(SLOT, KOFF) { _Pragma("unroll") for (int s = 0; s < 4; ++s) \
    ldslds16(gsA[s] + (KOFF), lds + (SLOT)*32768 + s*8192 + tid*16); }
#define STG_B(SLOT, KOFF) { _Pragma("unroll") for (int s = 0; s < 4; ++s) \
    ldslds16(gsB[s] + (KOFF), lds + 98304 + (SLOT)*32768 + s*8192 + tid*16); }

#define RD_FRAGS(BK, ASLOT, BSLOT, KC) { \
  _Pragma("unroll") for (int mf = 0; mf < 4; ++mf) \
    af[BK][mf] = *(const bf16x8*)(lds + (ASLOT)*32768 + aoff[mf] + (KC)); \
  _Pragma("unroll") for (int nf = 0; nf < 2; ++nf) \
    bq[BK][nf] = *(const bf16x8*)(lds + (BSLOT)*32768 + boff[nf] + (KC)); }

#define DO_MFMA(BK) { __builtin_amdgcn_s_setprio(1); \
  _Pragma("unroll") for (int mf = 0; mf < 4; ++mf) \
  _Pragma("unroll") for (int nf = 0; nf < 2; ++nf) \
    acc[mf][nf] = __builtin_amdgcn_mfma_f32_32x32x16_bf16(af[BK][mf], bq[BK][nf], acc[mf][nf], 0, 0, 0); \
  __builtin_amdgcn_s_setprio(0); }

#define BAR_FENCE() { __builtin_amdgcn_s_barrier(); asm volatile("" ::: "memory"); }

template<int NT>
__device__ __forceinline__ void core256(
    const char* Aseg, long long lda, long long arow0,
    const char* Bseg, long long ldb, long long bcol0,
    char* lds, int tid, f32x16 (&acc)[4][2]) {
  const int lane = tid & 63, wid = tid >> 6;
  const int wm = wid >> 2, wn = wid & 3;
  const int l31 = lane & 31, kg = (lane >> 5) * 16;
  const int C = (l31 & 7) << 4;
  int kcol[4];
#pragma unroll
  for (int ks = 0; ks < 4; ++ks) kcol[ks] = (ks * 32 + kg) ^ C;
  int aoff[4], boff[2];
#pragma unroll
  for (int mf = 0; mf < 4; ++mf) aoff[mf] = (wm * 128 + mf * 32 + l31) * 128;
#pragma unroll
  for (int nf = 0; nf < 2; ++nf) boff[nf] = 98304 + (wn * 64 + nf * 32 + l31) * 128;

  const int srow = tid >> 3, schunk = (tid & 7) * 16;
  const char* gsA[4]; const char* gsB[4];
#pragma unroll
  for (int s = 0; s < 4; ++s) {
    int rloc = s * 64 + srow;
    int sw = schunk ^ ((rloc & 7) << 4);
    gsA[s] = Aseg + (arow0 + rloc) * lda + sw;
    gsB[s] = Bseg + (bcol0 + rloc) * ldb + sw;
  }

  bf16x8 af[2][4], bq[2][2];

  // prologue: A(0), B(0), A(1) — vmcnt(4) retires A0,B0; A1 stays in flight
  STG_A(0, 0);
  STG_B(0, 0);
  STG_A(1, 128);
  asm volatile("s_waitcnt vmcnt(4)" ::: "memory");
  BAR_FENCE();
  RD_FRAGS(0, 0, 0, kcol[0]);

  int ia = 0, ib = 0;
  for (int t = 0; t < NT; ++t) {
    int iaw = ia + 2; if (iaw >= 3) iaw -= 3;      // (t+2)%3
    const int ibw = ib ^ 1;
    // issue order matters for counted vmcnt: B(t+1) first, then A(t+2)
    if (t + 1 < NT) STG_B(ibw, (long long)(t + 1) * 128);
    if (t + 2 < NT) STG_A(iaw, (long long)(t + 2) * 128);

    RD_FRAGS(1, ia, ib, kcol[1]);   // ks1 frags
    DO_MFMA(0);                     // ks0
    RD_FRAGS(0, ia, ib, kcol[2]);   // ks2 frags
    DO_MFMA(1);                     // ks1
    RD_FRAGS(1, ia, ib, kcol[3]);   // ks3 frags
    DO_MFMA(0);                     // ks2

    if (t + 1 < NT) {
      // boundary: retire {A(t+1), B(t+1)}, keep A(t+2) in flight
      if (t + 2 < NT) { asm volatile("s_waitcnt vmcnt(4)" ::: "memory"); }
      else            { asm volatile("s_waitcnt vmcnt(0)" ::: "memory"); }
      BAR_FENCE();
      int ian = ia + 1; if (ian >= 3) ian -= 3;
      RD_FRAGS(0, ian, ibw, kcol[0]);   // next tile ks0 frags (overlap ks3 MFMA)
      DO_MFMA(1);                       // ks3
      ia = ian; ib = ibw;
    } else {
      DO_MFMA(1);                       // final ks3
    }
  }
}

// map compact g -> (seg, tm, rowstart, rows)
__device__ __forceinline__ bool seg_map(int g, const int* __restrict__ counts,
                                        const int* __restrict__ meta,
                                        int& seg, int& tm, int& rowstart, int& rows) {
  if (g < 32) { seg = 0; tm = g; rowstart = 0; rows = TOK; return true; }
  int gr = g - 32;
  if (gr >= meta[16]) return false;
  int e = 0;
  while (gr >= meta[8 + e + 1]) ++e;
  seg = e + 1; tm = gr - meta[8 + e];
  rowstart = meta[e]; rows = counts[e];
  return true;
}

// ---------------- GEMM1: x @ w1t(permuted) -> SwiGLU -> hs bf16 ----------------
__global__ __launch_bounds__(512, 2)
void gemm1_kernel(const u16* __restrict__ xb, const u16* __restrict__ xg,
                  const u16* __restrict__ w1t, const float* __restrict__ sb1,
                  const float* __restrict__ rb1, const int* __restrict__ counts,
                  const int* __restrict__ meta, u16* __restrict__ hs) {
  __shared__ __align__(16) char lds[163840];
  // XCD chunking: XCD = lin&7 owns tn in [4x, 4x+4) -> B working set 2 MB (L2-fit)
  const int lin = blockIdx.x + 32 * blockIdx.y;
  const int tn = (lin & 7) * 4 + ((lin >> 3) & 3);
  const int g = lin >> 5;
  int seg, tm, rowstart, rows;
  if (!seg_map(g, counts, meta, seg, tm, rowstart, rows)) return;
  const u16* A = (seg == 0) ? xb : xg;
  const int hsbase = (seg == 0) ? 0 : TOK + rowstart;
  const int tid = threadIdx.x, lane = tid & 63, wid = tid >> 6;
  const int wm = wid >> 2, wn = wid & 3;

  f32x16 acc[4][2] = {};
  core256<DD / 64>((const char*)A, DD * 2, rowstart + (long long)tm * 256,
                   (const char*)(w1t + (size_t)seg * TWOF * DD), DD * 2,
                   (long long)tn * 256, lds, tid, acc);

  const int l31 = lane & 31, lg = lane >> 5;
  const int rlim = rows - tm * 256;
  const float* b1 = (seg == 0) ? sb1 : rb1 + (size_t)(seg - 1) * TWOF;
  const int f = (tn * 4 + wn) * 32 + l31;
  const float ba = b1[f], bb = b1[FF + f];
  u16* hbase = hs + (size_t)(hsbase + tm * 256) * FF;
#pragma unroll
  for (int mf = 0; mf < 4; ++mf)
#pragma unroll
    for (int reg = 0; reg < 16; ++reg) {
      int lr = wm * 128 + mf * 32 + (reg & 3) + 8 * (reg >> 2) + 4 * lg;
      if (lr < rlim) {
        float av = acc[mf][0][reg] + ba;
        float bv = acc[mf][1][reg] + bb;
        float sv = av / (1.0f + __expf(-av)) * bv;
        hbase[(size_t)lr * FF + f] = f2b(sv);
      }
    }
}

// ---------------- GEMM2: hs @ w2t -> yo (f32, all segments, no atomics) ----------------
__global__ __launch_bounds__(512, 2)
void gemm2_kernel(const u16* __restrict__ hs, const u16* __restrict__ w2t,
                  const float* __restrict__ sb2, const float* __restrict__ rb2,
                  const int* __restrict__ counts, const int* __restrict__ meta,
                  float* __restrict__ yo) {
  __shared__ __align__(16) char lds[163840];
  const int tn = blockIdx.x;                        // 4 tn
  const int g = blockIdx.y;
  int seg, tm, rowstart, rows;
  if (!seg_map(g, counts, meta, seg, tm, rowstart, rows)) return;
  const int hrow0 = (seg == 0) ? 0 : TOK + rowstart;
  const int tid = threadIdx.x, lane = tid & 63, wid = tid >> 6;
  const int wm = wid >> 2, wn = wid & 3;

  f32x16 acc[4][2] = {};
  core256<FF / 64>((const char*)hs, FF * 2, hrow0 + (long long)tm * 256,
                   (const char*)(w2t + (size_t)seg * DD * FF), FF * 2,
                   (long long)tn * 256, lds, tid, acc);

  const int l31 = lane & 31, lg = lane >> 5;
  const int rlim = rows - tm * 256;
  const float* b2 = (seg == 0) ? sb2 : rb2 + (size_t)(seg - 1) * DD;
  const int c0 = tn * 256 + wn * 64 + l31;
  const float bias0 = b2[c0], bias1 = b2[c0 + 32];
  float* ybase = yo + (size_t)(hrow0 + tm * 256) * DD;
#pragma unroll
  for (int mf = 0; mf < 4; ++mf)
#pragma unroll
    for (int reg = 0; reg < 16; ++reg) {
      int lr = wm * 128 + mf * 32 + (reg & 3) + 8 * (reg >> 2) + 4 * lg;
      if (lr < rlim) {
        float* orow = ybase + (size_t)lr * DD;
        orow[c0]      = acc[mf][0][reg] + bias0;
        orow[c0 + 32] = acc[mf][1][reg] + bias1;
      }
    }
}

// ---------------- combine: out[t] = yo[t] + w0*yo[T+s0] + w1*yo[T+s1] ----------------
__global__ void combine_kernel(const float* __restrict__ yo, const int* __restrict__ t2s,
                               const float* __restrict__ ew, float* __restrict__ out) {
  const int t = blockIdx.x, d = threadIdx.x;   // 256 threads x 4 floats
  const float4 a  = ((const float4*)(yo + (size_t)t * DD))[d];
  const int s0 = t2s[2*t], s1 = t2s[2*t+1];
  const float w0 = ew[2*t], w1 = ew[2*t+1];
  const float4 r0 = ((const float4*)(yo + (size_t)(TOK + s0) * DD))[d];
  const float4 r1 = ((const float4*)(yo + (size_t)(TOK + s1) * DD))[d];
  float4 r;
  r.x = a.x + w0 * r0.x + w1 * r1.x;
  r.y = a.y + w0 * r0.y + w1 * r1.y;
  r.z = a.z + w0 * r0.z + w1 * r1.z;
  r.w = a.w + w0 * r0.w + w1 * r1.w;
  ((float4*)(out + (size_t)t * DD))[d] = r;
}

// ---------------- launch ----------------
extern "C" void kernel_launch(void* const* d_in, const int* in_sizes, int n_in,
                              void* d_out, int out_size, void* d_ws, size_t ws_size,
                              hipStream_t stream) {
  const float* x   = (const float*)d_in[0];
  const float* gw  = (const float*)d_in[1];
  const float* gb  = (const float*)d_in[2];
  const float* sw1 = (const float*)d_in[3];
  const float* sb1 = (const float*)d_in[4];
  const float* sw2 = (const float*)d_in[5];
  const float* sb2 = (const float*)d_in[6];
  const float* rw1 = (const float*)d_in[7];
  const float* rb1 = (const float*)d_in[8];
  const float* rw2 = (const float*)d_in[9];
  const float* rb2 = (const float*)d_in[10];
  float* out = (float*)d_out;

  char* p = (char*)d_ws;
  auto alloc = [&](size_t bytes) { char* r = p; p += (bytes + 255) & ~(size_t)255; return r; };
  int*   counts = (int*)alloc(EE * 4);
  int*   meta   = (int*)alloc(17 * 4);
  int*   eidx   = (int*)alloc((size_t)2 * TOK * 4);
  int*   epos   = (int*)alloc((size_t)2 * TOK * 4);
  float* ew     = (float*)alloc((size_t)2 * TOK * 4);
  int*   s2t    = (int*)alloc((size_t)PADT * 4);
  float* swt    = (float*)alloc((size_t)PADT * 4);
  int*   t2s    = (int*)alloc((size_t)2 * TOK * 4);
  u16*   xb     = (u16*)alloc((size_t)TOK * DD * 2);
  u16*   xg     = (u16*)alloc((size_t)PADT * DD * 2);
  u16*   w1t    = (u16*)alloc((size_t)9 * TWOF * DD * 2);
  u16*   w2t    = (u16*)alloc((size_t)9 * DD * FF * 2);
  u16*   hs     = (u16*)alloc((size_t)(TOK + PADT + 256) * FF * 2);
  // yo aliases w1t: gemm2 runs strictly after gemm1 (same stream); ~110MB <= 151MB
  float* yo     = (float*)w1t;

  hipMemsetAsync(counts, 0, EE * 4, stream);
  hipMemsetAsync(s2t, 0, (size_t)PADT * 4, stream);
  gate_kernel<<<TOK / 4, 256, 0, stream>>>(x, gw, gb, counts, eidx, epos, ew);
  setup_kernel<<<1, 64, 0, stream>>>(counts, meta);
  slot_kernel<<<(2 * TOK) / 256, 256, 0, stream>>>(eidx, epos, ew, meta, s2t, swt, t2s);
  cvtx_kernel<<<(TOK * DD / 4) / 256, 256, 0, stream>>>(x, xb);
  gather_kernel<<<PADT / 2, 256, 0, stream>>>(xb, s2t, xg);
  wt_kernel<<<dim3(TWOF / 32, DD / 32, 9), 256, 0, stream>>>(sw1, rw1, w1t, DD, TWOF, 1);
  wt_kernel<<<dim3(DD / 32, FF / 32, 9), 256, 0, stream>>>(sw2, rw2, w2t, FF, DD, 0);
  gemm1_kernel<<<dim3(32, 104), 512, 0, stream>>>(xb, xg, w1t, sb1, rb1, counts, meta, hs);
  gemm2_kernel<<<dim3(4, 104), 512, 0, stream>>>(hs, w2t, sb2, rb2, counts, meta, yo);
  combine_kernel<<<TOK, 256, 0, stream>>>(yo, t2s, ew, out);
}